// Round 1
// baseline (1551.447 us; speedup 1.0000x reference)
//
#include <hip/hip_runtime.h>

typedef unsigned short u16;
typedef __attribute__((ext_vector_type(8))) short s8v;   // 8 bf16 (as shorts) = 4 VGPRs
typedef __attribute__((ext_vector_type(4))) float f4v;   // MFMA C/D frag

constexpr int B_ = 8, C_ = 256, F_ = 64, T_ = 500, H_ = 512;
constexpr int TT = 30;        // output t-columns per block
constexpr int S_ = 32;        // slots = TT + 2 (halo)
constexpr int NTILE = 17;     // ceil(500/30)

constexpr int XSROW = 260;    // floats / xs row  (rows 1040B: 16B-aligned, bank-skewed)
constexpr int HROW  = 520;    // u16   / hb,h2b row (rows 1040B: 16B-aligned)
constexpr int OROW  = 33;     // floats / outb row

constexpr int OFF_XS  = 0;                 // 32*260*4 = 33280
constexpr int OFF_H2  = 33280;             // 32*520*2 = 33280
constexpr int OFF_HB  = 66560;             // 32*520*2 = 33280 (dead after depthwise)
constexpr int OFF_OB  = 66560;             // aliases HB: 256*33*4 = 33792 -> ends 100352
constexpr int OFF_SM  = 100352;            // 32 f32
constexpr int OFF_SR  = 100480;            // 32 f32
constexpr int SMEM_BYTES = 100608;

__device__ __forceinline__ u16 f2bf(float f) {
  unsigned u = __float_as_uint(f);
  u += 0x7FFFu + ((u >> 16) & 1u);        // RNE
  return (u16)(u >> 16);
}
__device__ __forceinline__ float bf2f(u16 h) {
  return __uint_as_float(((unsigned)h) << 16);
}
__device__ __forceinline__ s8v cvt8(const float* p) {   // 8 f32 (16B-aligned LDS) -> bf16x8
  f4v lo = *(const f4v*)p;
  f4v hi = *(const f4v*)(p + 4);
  s8v r;
  r[0] = (short)f2bf(lo[0]); r[1] = (short)f2bf(lo[1]);
  r[2] = (short)f2bf(lo[2]); r[3] = (short)f2bf(lo[3]);
  r[4] = (short)f2bf(hi[0]); r[5] = (short)f2bf(hi[1]);
  r[6] = (short)f2bf(hi[2]); r[7] = (short)f2bf(hi[3]);
  return r;
}

__global__ void prep_kernel(const float* __restrict__ pw, const float* __restrict__ qw,
                            u16* __restrict__ wa, u16* __restrict__ wb) {
  int i = blockIdx.x * blockDim.x + threadIdx.x;   // 131072 threads exactly
  wa[i] = f2bf(pw[i]);
  wb[i] = f2bf(qw[i]);
}

__global__ __launch_bounds__(512)
void mixer_kernel(const float* __restrict__ x, const float* __restrict__ state,
                  const float* __restrict__ pre_b, const float* __restrict__ pre_nw,
                  const float* __restrict__ pre_nb,
                  const float* __restrict__ dw_w, const float* __restrict__ dw_b,
                  const float* __restrict__ dw_nw, const float* __restrict__ dw_nb,
                  const float* __restrict__ post_b, const float* __restrict__ post_nw,
                  const float* __restrict__ post_nb,
                  const u16* __restrict__ wpre, const u16* __restrict__ wpost,
                  float* __restrict__ out0, float* __restrict__ out1) {
  extern __shared__ char smem[];
  float* xs    = (float*)(smem + OFF_XS);   // [S_][XSROW]  x tile, f32 (GEMM1 A + residual)
  u16*   h2b   = (u16*)  (smem + OFF_H2);   // [S_][HROW]   h2 (post-dw), bf16
  u16*   hb    = (u16*)  (smem + OFF_HB);   // [S_][HROW]   h (post-pre), bf16
  float* outb  = (float*)(smem + OFF_OB);   // [C_][OROW]   GEMM2 raw out (aliases hb)
  float* statm = (float*)(smem + OFF_SM);
  float* statr = (float*)(smem + OFF_SR);

  const int tid  = threadIdx.x;
  const int bx   = blockIdx.x;
  const int tile = bx % NTILE;
  const int f    = (bx / NTILE) % F_;
  const int b    = bx / (NTILE * F_);
  const int t0   = tile * TT;

  const int w    = tid >> 6;        // wave 0..7
  const int lane = tid & 63;
  const int quad = lane >> 4;
  const int l16  = lane & 15;

  // ---- P0: stage x tile (slots s=0..31 -> t = t0-2+s), zero OOB ----
  {
    const float* xp = x + ((size_t)b * C_ * F_ + f) * T_;
    for (int e = tid; e < C_ * S_; e += 512) {
      int c = e >> 5, s = e & 31;
      int t = t0 - 2 + s;
      float v = 0.f;
      if (t >= 0 && t < T_) v = xp[(size_t)c * F_ * T_ + t];
      xs[s * XSROW + c] = v;
    }
  }
  __syncthreads();

  // ---- P1: GEMM1  D[s][o] = x^T * pre_w^T ;  relu(+pre_b) -> hb (bf16) ----
  {
    f4v acc[2][4];
#pragma unroll
    for (int mi = 0; mi < 2; mi++)
#pragma unroll
      for (int j = 0; j < 4; j++) acc[mi][j] = (f4v){0.f, 0.f, 0.f, 0.f};

    const u16* wp[4];
#pragma unroll
    for (int j = 0; j < 4; j++)
      wp[j] = wpre + ((w + 8 * j) * 16 + l16) * C_ + quad * 8;
    const float* a0p = &xs[l16 * XSROW + quad * 8];
    const float* a1p = &xs[(16 + l16) * XSROW + quad * 8];

#pragma unroll 2
    for (int k = 0; k < 8; k++) {
      int c0 = k * 32;
      s8v af0 = cvt8(a0p + c0);
      s8v af1 = cvt8(a1p + c0);
#pragma unroll
      for (int j = 0; j < 4; j++) {
        s8v bf = *(const s8v*)(wp[j] + c0);
        acc[0][j] = __builtin_amdgcn_mfma_f32_16x16x32_bf16(af0, bf, acc[0][j], 0, 0, 0);
        acc[1][j] = __builtin_amdgcn_mfma_f32_16x16x32_bf16(af1, bf, acc[1][j], 0, 0, 0);
      }
    }
#pragma unroll
    for (int j = 0; j < 4; j++) {
      int o = (w + 8 * j) * 16 + l16;
      float pb = pre_b[o];
#pragma unroll
      for (int mi = 0; mi < 2; mi++)
#pragma unroll
        for (int r2 = 0; r2 < 4; r2++) {
          int s = mi * 16 + quad * 4 + r2;      // D row = m
          float v = fmaxf(acc[mi][j][r2] + pb, 0.f);
          hb[s * HROW + o] = f2bf(v);
        }
    }
  }
  __syncthreads();

  // ---- P2: per-slot stats over 512 ch + normalize in place (16 thr / row) ----
  {
    int r = tid >> 4, p = tid & 15;
    u16* row = hb + r * HROW;
    float sum = 0.f, ss = 0.f;
#pragma unroll 8
    for (int i = 0; i < 32; i++) {
      float v = bf2f(row[p + (i << 4)]);
      sum += v; ss += v * v;
    }
#pragma unroll
    for (int mm = 1; mm < 16; mm <<= 1) {
      sum += __shfl_xor(sum, mm, 16);
      ss  += __shfl_xor(ss,  mm, 16);
    }
    float mean = sum * (1.f / 512.f);
    float var  = ss * (1.f / 512.f) - mean * mean;
    float rs   = rsqrtf(var + 1e-8f);
#pragma unroll 8
    for (int i = 0; i < 32; i++) {
      int o = p + (i << 4);
      float v = bf2f(row[o]);
      v = (v - mean) * rs * pre_nw[o] + pre_nb[o];
      row[o] = f2bf(v);
    }
  }
  __syncthreads();

  // ---- P3: edges. tile0: halo slots 0,1 <- raw state. last tile: emit new_state ----
  {
    int o = tid;   // 512 threads == H_
    if (tile == 0) {
      const float* sp = state + (((size_t)b * H_ + o) * F_ + f) * 2;
      hb[0 * HROW + o] = f2bf(sp[0]);
      hb[1 * HROW + o] = f2bf(sp[1]);
    }
    if (tile == NTILE - 1) {
      float* op = out1 + (((size_t)b * H_ + o) * F_ + f) * 2;
      op[0] = bf2f(hb[(T_ - t0) * HROW + o]);       // slot of t=498
      op[1] = bf2f(hb[(T_ - t0 + 1) * HROW + o]);   // slot of t=499
    }
  }
  __syncthreads();

  // ---- P4: depthwise K=3 along t + relu -> h2b (bf16); pad rows 30,31 = 0 ----
  {
    int o = tid;
    float w0 = dw_w[o * 3 + 0], w1 = dw_w[o * 3 + 1], w2 = dw_w[o * 3 + 2];
    float db = dw_b[o];
    float v0 = bf2f(hb[0 * HROW + o]);
    float v1 = bf2f(hb[1 * HROW + o]);
#pragma unroll 6
    for (int s = 2; s < 32; s++) {
      float v2 = bf2f(hb[s * HROW + o]);
      int t = t0 + s - 2;
      float r = fmaxf(w0 * v0 + w1 * v1 + w2 * v2 + db, 0.f);
      h2b[(s - 2) * HROW + o] = (t < T_) ? f2bf(r) : (u16)0;
      v0 = v1; v1 = v2;
    }
    h2b[30 * HROW + o] = 0;
    h2b[31 * HROW + o] = 0;
  }
  __syncthreads();

  // ---- P5: stats+normalize h2b rows 0..29 ----
  {
    int r = tid >> 4, p = tid & 15;
    if (r < TT) {
      u16* row = h2b + r * HROW;
      float sum = 0.f, ss = 0.f;
#pragma unroll 8
      for (int i = 0; i < 32; i++) {
        float v = bf2f(row[p + (i << 4)]);
        sum += v; ss += v * v;
      }
#pragma unroll
      for (int mm = 1; mm < 16; mm <<= 1) {
        sum += __shfl_xor(sum, mm, 16);
        ss  += __shfl_xor(ss,  mm, 16);
      }
      float mean = sum * (1.f / 512.f);
      float var  = ss * (1.f / 512.f) - mean * mean;
      float rs   = rsqrtf(var + 1e-8f);
#pragma unroll 8
      for (int i = 0; i < 32; i++) {
        int o = p + (i << 4);
        float v = bf2f(row[o]);
        v = (v - mean) * rs * dw_nw[o] + dw_nb[o];
        row[o] = f2bf(v);
      }
    }
  }
  __syncthreads();

  // ---- P6: GEMM2  D[c][s2] = post_w * h2 -> outb (f32, raw) ----
  {
    f4v acc[2][2];
#pragma unroll
    for (int mi = 0; mi < 2; mi++)
#pragma unroll
      for (int ni = 0; ni < 2; ni++) acc[mi][ni] = (f4v){0.f, 0.f, 0.f, 0.f};

    const u16* ap0 = wpost + ((2 * w + 0) * 16 + l16) * H_ + quad * 8;
    const u16* ap1 = wpost + ((2 * w + 1) * 16 + l16) * H_ + quad * 8;
    const u16* bp0 = h2b + (0 + l16) * HROW + quad * 8;
    const u16* bp1 = h2b + (16 + l16) * HROW + quad * 8;

#pragma unroll 4
    for (int k = 0; k < 16; k++) {
      int ko = k * 32;
      s8v a0 = *(const s8v*)(ap0 + ko);
      s8v a1 = *(const s8v*)(ap1 + ko);
      s8v b0 = *(const s8v*)(bp0 + ko);
      s8v b1 = *(const s8v*)(bp1 + ko);
      acc[0][0] = __builtin_amdgcn_mfma_f32_16x16x32_bf16(a0, b0, acc[0][0], 0, 0, 0);
      acc[0][1] = __builtin_amdgcn_mfma_f32_16x16x32_bf16(a0, b1, acc[0][1], 0, 0, 0);
      acc[1][0] = __builtin_amdgcn_mfma_f32_16x16x32_bf16(a1, b0, acc[1][0], 0, 0, 0);
      acc[1][1] = __builtin_amdgcn_mfma_f32_16x16x32_bf16(a1, b1, acc[1][1], 0, 0, 0);
    }
#pragma unroll
    for (int mi = 0; mi < 2; mi++)
#pragma unroll
      for (int ni = 0; ni < 2; ni++)
#pragma unroll
        for (int r2 = 0; r2 < 4; r2++) {
          int c  = (2 * w + mi) * 16 + quad * 4 + r2;
          int s2 = ni * 16 + l16;
          outb[c * OROW + s2] = acc[mi][ni][r2];
        }
  }
  __syncthreads();

  // ---- P7: per-column stats over 256 ch (with +post_b) -> statm/statr ----
  {
    int s2 = tid >> 4, p = tid & 15;
    if (s2 < TT) {
      float sum = 0.f, ss = 0.f;
#pragma unroll 4
      for (int i = 0; i < 16; i++) {
        int c = p + (i << 4);
        float v = outb[c * OROW + s2] + post_b[c];
        sum += v; ss += v * v;
      }
#pragma unroll
      for (int mm = 1; mm < 16; mm <<= 1) {
        sum += __shfl_xor(sum, mm, 16);
        ss  += __shfl_xor(ss,  mm, 16);
      }
      float mean = sum * (1.f / 256.f);
      float var  = ss * (1.f / 256.f) - mean * mean;
      float rs   = rsqrtf(var + 1e-8f);
      if (p == 0) { statm[s2] = mean; statr[s2] = rs; }
    }
  }
  __syncthreads();

  // ---- P8: final norm + residual + coalesced store ----
  {
    int cg  = tid >> 5;      // 0..15 (c within group of 16)
    int tt2 = tid & 31;      // t within tile
    if (tt2 < TT && (t0 + tt2) < T_) {
      int t = t0 + tt2;
      float m = statm[tt2], rs = statr[tt2];
      for (int cb = 0; cb < C_; cb += 16) {
        int c = cb + cg;
        float v  = outb[c * OROW + tt2] + post_b[c];
        float ov = (v - m) * rs * post_nw[c] + post_nb[c] + xs[(tt2 + 2) * XSROW + c];
        out0[(((size_t)b * C_ + c) * F_ + f) * T_ + t] = ov;
      }
    }
  }
}

extern "C" void kernel_launch(void* const* d_in, const int* in_sizes, int n_in,
                              void* d_out, int out_size, void* d_ws, size_t ws_size,
                              hipStream_t stream) {
  const float* x       = (const float*)d_in[0];
  const float* state   = (const float*)d_in[1];
  const float* pre_w   = (const float*)d_in[2];
  const float* pre_b   = (const float*)d_in[3];
  const float* pre_nw  = (const float*)d_in[4];
  const float* pre_nb  = (const float*)d_in[5];
  const float* dw_w    = (const float*)d_in[6];
  const float* dw_b    = (const float*)d_in[7];
  const float* dw_nw   = (const float*)d_in[8];
  const float* dw_nb   = (const float*)d_in[9];
  const float* post_w  = (const float*)d_in[10];
  const float* post_b  = (const float*)d_in[11];
  const float* post_nw = (const float*)d_in[12];
  const float* post_nb = (const float*)d_in[13];

  float* out0 = (float*)d_out;
  float* out1 = out0 + (size_t)B_ * C_ * F_ * T_;

  u16* wpre  = (u16*)d_ws;            // 512KB of ws: bf16 weights (rebuilt every call)
  u16* wpost = wpre + H_ * C_;

  prep_kernel<<<dim3((H_ * C_) / 512), dim3(512), 0, stream>>>(pre_w, post_w, wpre, wpost);
  mixer_kernel<<<dim3(B_ * F_ * NTILE), dim3(512), SMEM_BYTES, stream>>>(
      x, state, pre_b, pre_nw, pre_nb, dw_w, dw_b, dw_nw, dw_nb,
      post_b, post_nw, post_nb, wpre, wpost, out0, out1);
}